// Round 2
// baseline (240.841 us; speedup 1.0000x reference)
//
#include <hip/hip_runtime.h>
#include <hip/hip_fp16.h>

// QLinear with per-k fp16 requantized accumulation (mptorch fma semantics).
// out = q16( q16_scan_fma( q8(x) @ q8(W)^T ) + q8(b) )
//
// Round-2 structure: wave spans n (tn=0..63, 4n each); each wave owns an
// 8-row m-group -> x for a k-pair is ONE wave-uniform 32-B segment, loaded
// directly from global (L2-resident), off the LDS pipe entirely.
// w pre-interleaved as wI[K/2][N/4][{k0,k1}x{n0..n3}] so one ds_read_b128
// per k-pair feeds 32 v_pk_fma_f16 (op_sel lo/hi broadcasts the packed k).
// Per-CU per k-pair: VALU 64 cyc (wall), LDS ~48, VMEM ~40 -> VALU-bound.

#define M_DIM 2048
#define N_DIM 1024
#define K_DIM 1024

#define BM 16
#define BN 256
#define BK 64
#define NCHUNK (K_DIM / BK)   // 16

typedef unsigned u32;

// exact E4M3 (exp=4, man=3) quantization of an fp32 value, result fp32
__device__ __forceinline__ float quant_e4m3(float v) {
  unsigned au = __float_as_uint(v) & 0x7fffffffu;
  if (au == 0u) return v;                 // +-0
  int e = (int)(au >> 23) - 127;          // floor(log2|v|) for normals
  if (e < -6) e = -6;                     // fp32 subnorms hit the clamp too
  float s  = __uint_as_float((unsigned)(130 - e) << 23);  // 2^(3-e), exact
  float is = __uint_as_float((unsigned)(124 + e) << 23);  // 2^(e-3), exact
  float r = rintf(v * s) * is;            // RNE (half-to-even), all steps exact
  return fminf(240.f, fmaxf(-240.f, r));
}

// ---------- quant/transpose prep kernels ----------

// x path: in [R][C] fp32 -> out [C/2][R] uints; uint = {q(in[r][2t]), q(in[r][2t+1])}
__global__ __launch_bounds__(256) void qt_pack_kernel(const float* __restrict__ in,
                                                      u32* __restrict__ outp,
                                                      int R, int C) {
  __shared__ float tile[32][33];
  const int tx = threadIdx.x & 31;
  const int ty = threadIdx.x >> 5;
  const int c0 = blockIdx.x * 32;
  const int r0 = blockIdx.y * 32;
#pragma unroll
  for (int i = 0; i < 4; i++) {
    int r = r0 + ty + i * 8;
    tile[ty + i * 8][tx] = quant_e4m3(in[(size_t)r * C + c0 + tx]);
  }
  __syncthreads();
#pragma unroll
  for (int i = 0; i < 2; i++) {
    int tl = ty + i * 8;                   // k-pair index 0..15
    u32 lo = (u32)__half_as_ushort(__float2half(tile[tx][2 * tl]));
    u32 hi = (u32)__half_as_ushort(__float2half(tile[tx][2 * tl + 1]));
    outp[(size_t)(c0 / 2 + tl) * R + r0 + tx] = lo | (hi << 16);
  }
}

// w path: in [N][K] fp32 -> wI u32[K/2][N]; 16-B group (tp,n4) =
// halfs {w[2tp][4n4+0..3], w[2tp+1][4n4+0..3]} (c fastest, then j)
__global__ __launch_bounds__(256) void qt_wi_kernel(const float* __restrict__ in,
                                                    u32* __restrict__ outp) {
  __shared__ float tile[32][33];   // [n_local][k_local]
  const int tx = threadIdx.x & 31;
  const int ty = threadIdx.x >> 5;
  const int k0 = blockIdx.x * 32;
  const int n0 = blockIdx.y * 32;
#pragma unroll
  for (int i = 0; i < 4; i++) {
    int n = n0 + ty + i * 8;
    tile[ty + i * 8][tx] = quant_e4m3(in[(size_t)n * K_DIM + k0 + tx]);
  }
  __syncthreads();
  if (threadIdx.x < 128) {
    const int tpl = threadIdx.x >> 3;     // 0..15 (k-pair in tile)
    const int n4l = threadIdx.x & 7;      // 0..7  (n-group in tile)
    ushort h[8];
#pragma unroll
    for (int j = 0; j < 2; j++)
#pragma unroll
      for (int c = 0; c < 4; c++)
        h[j * 4 + c] = __half_as_ushort(__float2half(tile[n4l * 4 + c][tpl * 2 + j]));
    uint4 o;
    o.x = h[0] | ((u32)h[1] << 16);
    o.y = h[2] | ((u32)h[3] << 16);
    o.z = h[4] | ((u32)h[5] << 16);
    o.w = h[6] | ((u32)h[7] << 16);
    *reinterpret_cast<uint4*>(outp + (size_t)(k0 / 2 + tpl) * N_DIM + n0 + n4l * 4) = o;
  }
}

// ---------- GEMM ----------

__device__ __forceinline__ void gld16(const void* g, void* l) {
  __builtin_amdgcn_global_load_lds((const __attribute__((address_space(1))) u32*)g,
                                   (__attribute__((address_space(3))) u32*)l, 16, 0, 0);
}

// acc = pk_fma(splat(x.lo), w, acc)  -- k0 of the packed pair
__device__ __forceinline__ void pkfma_lo(u32& acc, u32 x, u32 w) {
  asm("v_pk_fma_f16 %0, %1, %2, %0 op_sel:[0,0,0] op_sel_hi:[0,1,1]"
      : "+v"(acc) : "v"(x), "v"(w));
}
// acc = pk_fma(splat(x.hi), w, acc)  -- k1 of the packed pair
__device__ __forceinline__ void pkfma_hi(u32& acc, u32 x, u32 w) {
  asm("v_pk_fma_f16 %0, %1, %2, %0 op_sel:[1,0,0] op_sel_hi:[1,1,1]"
      : "+v"(acc) : "v"(x), "v"(w));
}

// xP [K/2][M] u32 (packed k-pairs), wI u32[K/2][N] interleaved, b [N] fp32,
// out [M][N] fp32.  Block: 128 threads = 2 waves; tile 16(m) x 256(n);
// wave = one 8-row m-group x 256 n; thread tile 8m x 4n.
__global__ __launch_bounds__(128) void gemm_qfma(const u32* __restrict__ xP,
                                                 const u32* __restrict__ wI,
                                                 const float* __restrict__ b,
                                                 float* __restrict__ outp) {
  __shared__ __align__(16) u32 wsh[2][BK / 2][BN];   // 2 x 32 x 256 u32 = 64 KB
  const int tid = threadIdx.x;
  const int tn = tid & 63;          // n-thread, 4 halfs
  const int wid = tid >> 6;         // 0,1 : m-group (8 rows)
  const int bn0 = blockIdx.x * BN;
  const int bm0 = blockIdx.y * BM;

  u32 acc[8][2];
#pragma unroll
  for (int i = 0; i < 8; i++) { acc[i][0] = 0u; acc[i][1] = 0u; }

  // w staging: 16 passes x 16 B/thread; linear LDS (wave-uniform base + lane*16)
  const u32* wsrc = wI + (size_t)wid * N_DIM + bn0 + (tn << 2);
  char* wldst = (char*)&wsh[0][0][0] + tid * 16;

  auto stage = [&](int ch, int buf) {
    const u32* wp = wsrc + (size_t)ch * (BK / 2) * N_DIM;
    char* wl = wldst + buf * (BK / 2) * BN * 4;
#pragma unroll
    for (int p = 0; p < 16; p++)
      gld16(wp + (size_t)(p * 2) * N_DIM, wl + p * 2048);
  };

  const u32* xbase = xP + bm0 + (wid << 3);   // wave-uniform

  auto compute = [&](int ch, int buf) {
#pragma unroll
    for (int tp = 0; tp < BK / 2; tp++) {     // k-pair: k0=2tp, k1=2tp+1
      const u32* xr = xbase + (size_t)(ch * (BK / 2) + tp) * M_DIM;
      const uint4 xlo = *reinterpret_cast<const uint4*>(xr);      // m0..3
      const uint4 xhi = *reinterpret_cast<const uint4*>(xr + 4);  // m4..7
      const uint4 wv = *reinterpret_cast<const uint4*>(&wsh[buf][tp][tn << 2]);
      const u32 xm[8] = {xlo.x, xlo.y, xlo.z, xlo.w, xhi.x, xhi.y, xhi.z, xhi.w};
      // strict k order per accumulator: all k0 updates, then all k1 updates
#pragma unroll
      for (int i = 0; i < 8; i++) {
        pkfma_lo(acc[i][0], xm[i], wv.x);   // k0, n0n1
        pkfma_lo(acc[i][1], xm[i], wv.y);   // k0, n2n3
      }
#pragma unroll
      for (int i = 0; i < 8; i++) {
        pkfma_hi(acc[i][0], xm[i], wv.z);   // k1, n0n1
        pkfma_hi(acc[i][1], xm[i], wv.w);   // k1, n2n3
      }
    }
  };

  stage(0, 0);
  __syncthreads();
#pragma unroll 1
  for (int ch = 0; ch < NCHUNK; ch += 2) {
    stage(ch + 1, 1);          // issue next chunk's loads before compute
    compute(ch, 0);
    __syncthreads();
    if (ch + 2 < NCHUNK) stage(ch + 2, 0);
    compute(ch + 1, 1);
    __syncthreads();
  }

  // epilogue: out = fp16RNE(acc + q8(b)), stored fp32 (fp32 add exact here)
  const int nc = bn0 + (tn << 2);
  float4 bq;
  bq.x = quant_e4m3(b[nc + 0]);
  bq.y = quant_e4m3(b[nc + 1]);
  bq.z = quant_e4m3(b[nc + 2]);
  bq.w = quant_e4m3(b[nc + 3]);
#pragma unroll
  for (int i = 0; i < 8; i++) {
    __half2 a0 = *reinterpret_cast<__half2*>(&acc[i][0]);
    __half2 a1 = *reinterpret_cast<__half2*>(&acc[i][1]);
    float4 o;
    o.x = __half2float(__float2half(__low2float(a0)  + bq.x));
    o.y = __half2float(__float2half(__high2float(a0) + bq.y));
    o.z = __half2float(__float2half(__low2float(a1)  + bq.z));
    o.w = __half2float(__float2half(__high2float(a1) + bq.w));
    *reinterpret_cast<float4*>(outp + (size_t)(bm0 + (wid << 3) + i) * N_DIM + nc) = o;
  }
}

extern "C" void kernel_launch(void* const* d_in, const int* in_sizes, int n_in,
                              void* d_out, int out_size, void* d_ws, size_t ws_size,
                              hipStream_t stream) {
  const float* x = (const float*)d_in[0];   // [2048][1024]
  const float* w = (const float*)d_in[1];   // [1024][1024] (out_f, in_f)
  const float* b = (const float*)d_in[2];   // [1024]
  float* outp = (float*)d_out;              // [2048][1024] fp32

  char* ws = (char*)d_ws;
  u32* xP = (u32*)ws;                        // [K/2][M] u32, 4 MiB
  u32* wI = (u32*)(ws + (size_t)(4 << 20));  // [K/2][N] u32, 2 MiB

  hipLaunchKernelGGL(qt_pack_kernel, dim3(K_DIM / 32, M_DIM / 32), dim3(256), 0, stream,
                     x, xP, M_DIM, K_DIM);
  hipLaunchKernelGGL(qt_wi_kernel, dim3(K_DIM / 32, N_DIM / 32), dim3(256), 0, stream,
                     w, wI);
  hipLaunchKernelGGL(gemm_qfma, dim3(N_DIM / BN, M_DIM / BM), dim3(128), 0, stream,
                     xP, wI, b, outp);
}

// Round 3
// 112.390 us; speedup vs baseline: 2.1429x; 2.1429x over previous
//
#include <hip/hip_runtime.h>
#include <hip/hip_fp16.h>

// QLinear with per-k fp16 requantized accumulation (mptorch fma semantics).
// out = q16( q16_scan_fma( q8(x) @ q8(W)^T ) + q8(b) )
//
// Round-3: baseline geometry (256 thr, BM=32 x BN=128, 4m x 4n thread tile,
// 8 waves/CU) + cheap LDS feeds:
//  - x packed {k0,k1} per u32 -> one ds_read_b128 per k-pair, only 2 unique
//    addresses per wave (broadcast-served), op_sel splats k in-register.
//  - w interleaved wI[K/2][N]: 16-B group = {k0n01,k0n23,k1n01,k1n23} ->
//    one contiguous ds_read_b128 per k-pair.
// Per wave per k-pair: 2 LDS instr (~12 cyc) feeding 16 pk_fma (32 cyc).

#define M_DIM 2048
#define N_DIM 1024
#define K_DIM 1024

#define BM 32
#define BN 128
#define BK 64
#define NCHUNK (K_DIM / BK)   // 16

typedef unsigned u32;

// exact E4M3 (exp=4, man=3) quantization of an fp32 value, result fp32
__device__ __forceinline__ float quant_e4m3(float v) {
  unsigned au = __float_as_uint(v) & 0x7fffffffu;
  if (au == 0u) return v;                 // +-0
  int e = (int)(au >> 23) - 127;          // floor(log2|v|) for normals
  if (e < -6) e = -6;                     // fp32 subnorms hit the clamp too
  float s  = __uint_as_float((unsigned)(130 - e) << 23);  // 2^(3-e), exact
  float is = __uint_as_float((unsigned)(124 + e) << 23);  // 2^(e-3), exact
  float r = rintf(v * s) * is;            // RNE (half-to-even), all steps exact
  return fminf(240.f, fmaxf(-240.f, r));
}

// ---------- fused prep: x quant+pack-transpose, w quant+interleave ----------
// blocks [0,2048): x [M][K] -> xP[K/2][M], u32 = {q(x[m][2t]), q(x[m][2t+1])}
// blocks [2048,3072): w [N][K] -> wI[K/2][N], 16-B group (tp, n4) =
//   {k0:n0n1, k0:n2n3, k1:n0n1, k1:n2n3} as 4 u32
__global__ __launch_bounds__(256) void prep_kernel(const float* __restrict__ x,
                                                   const float* __restrict__ w,
                                                   u32* __restrict__ xP,
                                                   u32* __restrict__ wI) {
  __shared__ float tile[32][33];
  const int tx = threadIdx.x & 31;
  const int ty = threadIdx.x >> 5;
  if (blockIdx.x < 2048) {
    const int c0 = (blockIdx.x & 31) * 32;   // k offset
    const int r0 = (blockIdx.x >> 5) * 32;   // m offset
#pragma unroll
    for (int i = 0; i < 4; i++) {
      int r = r0 + ty + i * 8;
      tile[ty + i * 8][tx] = quant_e4m3(x[(size_t)r * K_DIM + c0 + tx]);
    }
    __syncthreads();
#pragma unroll
    for (int i = 0; i < 2; i++) {
      int tl = ty + i * 8;                   // k-pair index 0..15
      u32 lo = (u32)__half_as_ushort(__float2half(tile[tx][2 * tl]));
      u32 hi = (u32)__half_as_ushort(__float2half(tile[tx][2 * tl + 1]));
      xP[(size_t)(c0 / 2 + tl) * M_DIM + r0 + tx] = lo | (hi << 16);
    }
  } else {
    const int b = blockIdx.x - 2048;
    const int k0 = (b & 31) * 32;
    const int n0 = (b >> 5) * 32;
#pragma unroll
    for (int i = 0; i < 4; i++) {
      int n = n0 + ty + i * 8;
      tile[ty + i * 8][tx] = quant_e4m3(w[(size_t)n * K_DIM + k0 + tx]);
    }
    __syncthreads();
    if (threadIdx.x < 128) {
      const int tpl = threadIdx.x >> 3;     // 0..15 (k-pair in tile)
      const int n4l = threadIdx.x & 7;      // 0..7  (n-group in tile)
      ushort h[8];
#pragma unroll
      for (int j = 0; j < 2; j++)
#pragma unroll
        for (int c = 0; c < 4; c++)
          h[j * 4 + c] = __half_as_ushort(__float2half(tile[n4l * 4 + c][tpl * 2 + j]));
      uint4 o;
      o.x = h[0] | ((u32)h[1] << 16);
      o.y = h[2] | ((u32)h[3] << 16);
      o.z = h[4] | ((u32)h[5] << 16);
      o.w = h[6] | ((u32)h[7] << 16);
      *reinterpret_cast<uint4*>(wI + (size_t)(k0 / 2 + tpl) * N_DIM + n0 + n4l * 4) = o;
    }
  }
}

// ---------- GEMM ----------

__device__ __forceinline__ void gld16(const void* g, void* l) {
  __builtin_amdgcn_global_load_lds((const __attribute__((address_space(1))) u32*)g,
                                   (__attribute__((address_space(3))) u32*)l, 16, 0, 0);
}

// acc = pk_fma(splat(x.lo), w, acc)  -- k0 of the packed pair
__device__ __forceinline__ void pkfma_lo(u32& acc, u32 x, u32 w) {
  asm("v_pk_fma_f16 %0, %1, %2, %0 op_sel:[0,0,0] op_sel_hi:[0,1,1]"
      : "+v"(acc) : "v"(x), "v"(w));
}
// acc = pk_fma(splat(x.hi), w, acc)  -- k1 of the packed pair
__device__ __forceinline__ void pkfma_hi(u32& acc, u32 x, u32 w) {
  asm("v_pk_fma_f16 %0, %1, %2, %0 op_sel:[1,0,0] op_sel_hi:[1,1,1]"
      : "+v"(acc) : "v"(x), "v"(w));
}

// xP [K/2][M] u32, wI [K/2][N] u32 interleaved, b [N] fp32, out [M][N] fp32.
// 256 threads; tile 32(m) x 128(n); thread 4m x 4n; tn=tid&31, tm=tid>>5
// (tm spans 2 values per wave -> x ds_read_b128 is a 2-address broadcast).
__global__ __launch_bounds__(256, 2) void gemm_qfma(const u32* __restrict__ xP,
                                                    const u32* __restrict__ wI,
                                                    const float* __restrict__ b,
                                                    float* __restrict__ outp) {
  __shared__ __align__(16) u32 xs[2][BK / 2][BM];    // 2 x 32 x 32 u32  =  8 KB
  __shared__ __align__(16) u32 wsh[2][BK / 2][BN];   // 2 x 32 x 128 u32 = 32 KB
  const int tid = threadIdx.x;
  const int tn = tid & 31;
  const int tm = tid >> 5;
  const int bn0 = blockIdx.x * BN;
  const int bm0 = blockIdx.y * BM;

  u32 acc[4][2];
#pragma unroll
  for (int i = 0; i < 4; i++) { acc[i][0] = 0u; acc[i][1] = 0u; }

  // staging: linear LDS (wave-uniform base + lane*16), per-lane global src
  const u32* wsrc = wI + (size_t)(tid >> 5) * N_DIM + bn0 + ((tid & 31) << 2);
  const u32* xsrc = xP + (size_t)(tid >> 3) * M_DIM + bm0 + ((tid & 7) << 2);

  auto stage = [&](int ch, int buf) {
    const u32* wp = wsrc + (size_t)ch * (BK / 2) * N_DIM;
    char* wl = (char*)&wsh[buf][0][0] + tid * 16;
#pragma unroll
    for (int p = 0; p < 4; p++)                       // 32 x 128 u32, 16 KB
      gld16(wp + (size_t)(p * 8) * N_DIM, wl + p * 4096);
    gld16(xsrc + (size_t)ch * (BK / 2) * M_DIM,       // 32 x 32 u32, 4 KB
          (char*)&xs[buf][0][0] + tid * 16);
  };

  auto compute = [&](int buf) {
#pragma unroll
    for (int tp = 0; tp < BK / 2; tp++) {             // k-pair: k0=2tp, k1=2tp+1
      const uint4 xv = *reinterpret_cast<const uint4*>(&xs[buf][tp][tm << 2]);
      const uint4 wv = *reinterpret_cast<const uint4*>(&wsh[buf][tp][tn << 2]);
      // strict k order per accumulator: all k0 updates, then all k1 updates
      pkfma_lo(acc[0][0], xv.x, wv.x); pkfma_lo(acc[0][1], xv.x, wv.y);
      pkfma_lo(acc[1][0], xv.y, wv.x); pkfma_lo(acc[1][1], xv.y, wv.y);
      pkfma_lo(acc[2][0], xv.z, wv.x); pkfma_lo(acc[2][1], xv.z, wv.y);
      pkfma_lo(acc[3][0], xv.w, wv.x); pkfma_lo(acc[3][1], xv.w, wv.y);
      pkfma_hi(acc[0][0], xv.x, wv.z); pkfma_hi(acc[0][1], xv.x, wv.w);
      pkfma_hi(acc[1][0], xv.y, wv.z); pkfma_hi(acc[1][1], xv.y, wv.w);
      pkfma_hi(acc[2][0], xv.z, wv.z); pkfma_hi(acc[2][1], xv.z, wv.w);
      pkfma_hi(acc[3][0], xv.w, wv.z); pkfma_hi(acc[3][1], xv.w, wv.w);
    }
  };

  stage(0, 0);
  __syncthreads();
#pragma unroll 1
  for (int ch = 0; ch < NCHUNK; ch += 2) {
    stage(ch + 1, 1);          // issue next chunk's loads before compute
    compute(0);
    __syncthreads();
    if (ch + 2 < NCHUNK) stage(ch + 2, 0);
    compute(1);
    __syncthreads();
  }

  // epilogue: out = fp16RNE(acc + q8(b)), stored fp32 (fp32 add exact here)
  const int nc = bn0 + (tn << 2);
  float4 bq;
  bq.x = quant_e4m3(b[nc + 0]);
  bq.y = quant_e4m3(b[nc + 1]);
  bq.z = quant_e4m3(b[nc + 2]);
  bq.w = quant_e4m3(b[nc + 3]);
#pragma unroll
  for (int i = 0; i < 4; i++) {
    __half2 a0 = *reinterpret_cast<__half2*>(&acc[i][0]);
    __half2 a1 = *reinterpret_cast<__half2*>(&acc[i][1]);
    float4 o;
    o.x = __half2float(__float2half(__low2float(a0)  + bq.x));
    o.y = __half2float(__float2half(__high2float(a0) + bq.y));
    o.z = __half2float(__float2half(__low2float(a1)  + bq.z));
    o.w = __half2float(__float2half(__high2float(a1) + bq.w));
    *reinterpret_cast<float4*>(outp + (size_t)(bm0 + (tm << 2) + i) * N_DIM + nc) = o;
  }
}

extern "C" void kernel_launch(void* const* d_in, const int* in_sizes, int n_in,
                              void* d_out, int out_size, void* d_ws, size_t ws_size,
                              hipStream_t stream) {
  const float* x = (const float*)d_in[0];   // [2048][1024]
  const float* w = (const float*)d_in[1];   // [1024][1024] (out_f, in_f)
  const float* b = (const float*)d_in[2];   // [1024]
  float* outp = (float*)d_out;              // [2048][1024] fp32

  char* ws = (char*)d_ws;
  u32* xP = (u32*)ws;                        // [K/2][M] u32, 4 MiB
  u32* wI = (u32*)(ws + (size_t)(4 << 20));  // [K/2][N] u32, 2 MiB

  hipLaunchKernelGGL(prep_kernel, dim3(2048 + 1024), dim3(256), 0, stream,
                     x, w, xP, wI);
  hipLaunchKernelGGL(gemm_qfma, dim3(N_DIM / BN, M_DIM / BM), dim3(256), 0, stream,
                     xP, wI, b, outp);
}